// Round 9
// baseline (753.906 us; speedup 1.0000x reference)
//
#include <hip/hip_runtime.h>
#include <hip/hip_bf16.h>
#include <stdint.h>

// Problem constants (match reference)
#define N_NODES 50000
#define N_EDGES 300000
#define ET      3
#define D_IN    256
#define D_HID   256
#define D_OUT   128
#define KDIM    768          // ET * 256, fused-K for the single GEMM per layer
#define MPAD    50048        // 391 * 128 (GEMM row-tile padded)
#define NTOT    (ET * N_NODES)          // 150000 merged (etype,node) slots per layer
#define ETOT    (ET * N_EDGES)          // 900000 edges per layer
#define NTOT2   (2 * NTOT)              // both layers
#define ETOT2   (2 * ETOT)
#define NB2     ((NTOT2 + 1023) / 1024) // 293 scan blocks

typedef short bhalf8 __attribute__((ext_vector_type(8)));   // 8 bf16 (4 VGPRs)
typedef float f32x4  __attribute__((ext_vector_type(4)));

// bf16 helpers (RNE), bit-level to avoid header API differences
__device__ __forceinline__ unsigned short f2bf(float f) {
    union { float f; uint32_t u; } c; c.f = f;
    uint32_t u = c.u;
    uint32_t r = (u + 0x7fff + ((u >> 16) & 1)) >> 16;
    return (unsigned short)r;
}
__device__ __forceinline__ float bf2f(unsigned short b) {
    union { uint32_t u; float f; } c; c.u = ((uint32_t)b) << 16;
    return c.f;
}

__device__ __forceinline__ void glds16(const void* g, const void* l) {
    __builtin_amdgcn_global_load_lds(
        (const __attribute__((address_space(1))) unsigned int*)g,
        (__attribute__((address_space(3))) unsigned int*)l, 16, 0, 0);
}

// ---------------------------------------------------------------------------
// CSR build, BOTH graphs at once (merged slot space [2*NTOT]):
//   slot = layer*NTOT + e*N_NODES + dst
// One histogram -> one 3-kernel parallel scan -> one fill.
// Layer-1 edges sum to exactly ETOT, so rp[NTOT] == ETOT automatically and
// layer L's rows live at rp[L*NTOT + wid] with esrc positions global.
// ---------------------------------------------------------------------------

__global__ void hist2_kernel(const int* __restrict__ edges1, const int* __restrict__ edges2,
                             int* __restrict__ cnt) {
    int i = blockIdx.x * blockDim.x + threadIdx.x;
    if (i >= ETOT2) return;
    int layer = i / ETOT;
    int k = i - layer * ETOT;
    int e = k / N_EDGES;
    int j = k - e * N_EDGES;
    const int* edges = layer ? edges2 : edges1;
    int dst = edges[(e * 2 + 1) * N_EDGES + j];
    atomicAdd(&cnt[layer * NTOT + e * N_NODES + dst], 1);
}

// scan1: block b scans its 1024 counts (4/thread), writes block-local
// exclusive positions into rp and the block total into bsum[b].
__global__ __launch_bounds__(256) void scan1_kernel(const int* __restrict__ cnt,
                                                    int* __restrict__ rp,
                                                    int* __restrict__ bsum) {
    int b = blockIdx.x, t = threadIdx.x;
    int idx = b * 1024 + t * 4;
    int4 v = make_int4(0, 0, 0, 0);
    if (idx + 3 < NTOT2) v = *(const int4*)&cnt[idx];
    else {
        if (idx + 0 < NTOT2) v.x = cnt[idx + 0];
        if (idx + 1 < NTOT2) v.y = cnt[idx + 1];
        if (idx + 2 < NTOT2) v.z = cnt[idx + 2];
        if (idx + 3 < NTOT2) v.w = cnt[idx + 3];
    }
    int s = v.x + v.y + v.z + v.w;
    int lane = t & 63, w = t >> 6;
    int inc = s;
    #pragma unroll
    for (int d = 1; d < 64; d <<= 1) {
        int u = __shfl_up(inc, d, 64);
        if (lane >= d) inc += u;
    }
    __shared__ int ws[4];
    if (lane == 63) ws[w] = inc;
    __syncthreads();
    int wbase = 0;
    for (int i = 0; i < w; ++i) wbase += ws[i];
    int ebase = wbase + inc - s;   // block-local exclusive base for this thread
    if (idx + 0 < NTOT2) rp[idx + 0] = ebase;
    if (idx + 1 < NTOT2) rp[idx + 1] = ebase + v.x;
    if (idx + 2 < NTOT2) rp[idx + 2] = ebase + v.x + v.y;
    if (idx + 3 < NTOT2) rp[idx + 3] = ebase + v.x + v.y + v.z;
    if (t == 0) bsum[b] = ws[0] + ws[1] + ws[2] + ws[3];
}

// scan2: one block (512 threads); exclusive scan of the 293 block sums.
__global__ __launch_bounds__(512) void scan2_kernel(const int* __restrict__ bsum,
                                                    int* __restrict__ bbase) {
    int t = threadIdx.x;
    __shared__ int sh[512];
    int v = (t < NB2) ? bsum[t] : 0;
    sh[t] = v;
    __syncthreads();
    #pragma unroll
    for (int d = 1; d < 512; d <<= 1) {
        int u = (t >= d) ? sh[t - d] : 0;
        __syncthreads();
        sh[t] += u;
        __syncthreads();
    }
    if (t < NB2) bbase[t] = sh[t] - v;   // exclusive
}

// scan3: add block bases; emit final rowptr + cursor copy + sentinel.
__global__ void scan3_kernel(int* __restrict__ rp, int* __restrict__ cursor,
                             const int* __restrict__ bbase) {
    int i = blockIdx.x * blockDim.x + threadIdx.x;
    if (i < NTOT2) {
        int v = rp[i] + bbase[i >> 10];
        rp[i] = v;
        cursor[i] = v;
    }
    if (i == 0) rp[NTOT2] = ETOT2;
}

__global__ void fill2_kernel(const int* __restrict__ edges1, const int* __restrict__ edges2,
                             int* __restrict__ cursor, int* __restrict__ esrc) {
    int i = blockIdx.x * blockDim.x + threadIdx.x;
    if (i >= ETOT2) return;
    int layer = i / ETOT;
    int k = i - layer * ETOT;
    int e = k / N_EDGES;
    int j = k - e * N_EDGES;
    const int* edges = layer ? edges2 : edges1;
    int src = edges[(e * 2 + 0) * N_EDGES + j];
    int dst = edges[(e * 2 + 1) * N_EDGES + j];
    int p = atomicAdd(&cursor[layer * NTOT + e * N_NODES + dst], 1);   // global position
    esrc[p] = src;
}

// ---------------------------------------------------------------------------
// Aggregation (pull): one wave per (etype, node). Lane t owns channels
// [4t, 4t+4). 4-wide edge batching for memory-level parallelism. `base`
// selects the layer's slot range (0 or NTOT). ind[local wid] = (cnt>0).
// ---------------------------------------------------------------------------
__global__ void agg_kernel(const float* __restrict__ in, const int* __restrict__ rp,
                           const int* __restrict__ esrc, int base,
                           unsigned short* __restrict__ Xh, unsigned short* __restrict__ Xl,
                           float* __restrict__ ind) {
    int wid = (blockIdx.x * blockDim.x + threadIdx.x) >> 6;
    int lane = threadIdx.x & 63;
    if (wid >= NTOT) return;
    int e = wid / N_NODES;
    int n = wid - e * N_NODES;
    int r0 = rp[base + wid];
    int r1 = rp[base + wid + 1];
    int cntv = r1 - r0;
    float4 acc = make_float4(0.f, 0.f, 0.f, 0.f);
    int j = r0;
    // 4-wide batches: 4 independent index loads, then 4 gathers in flight
    for (; j + 4 <= r1; j += 4) {
        int s0 = esrc[j + 0];
        int s1 = esrc[j + 1];
        int s2 = esrc[j + 2];
        int s3 = esrc[j + 3];
        float4 v0 = *((const float4*)(in + (size_t)s0 * 256) + lane);
        float4 v1 = *((const float4*)(in + (size_t)s1 * 256) + lane);
        float4 v2 = *((const float4*)(in + (size_t)s2 * 256) + lane);
        float4 v3 = *((const float4*)(in + (size_t)s3 * 256) + lane);
        acc.x += v0.x + v1.x + v2.x + v3.x;
        acc.y += v0.y + v1.y + v2.y + v3.y;
        acc.z += v0.z + v1.z + v2.z + v3.z;
        acc.w += v0.w + v1.w + v2.w + v3.w;
    }
    for (; j < r1; ++j) {
        int s = esrc[j];
        float4 v = *((const float4*)(in + (size_t)s * 256) + lane);
        acc.x += v.x; acc.y += v.y; acc.z += v.z; acc.w += v.w;
    }
    float sc = (cntv > 0) ? (1.f / (float)cntv) : 0.f;
    acc.x *= sc; acc.y *= sc; acc.z *= sc; acc.w *= sc;
    union { ushort4 u; unsigned long long ll; } ph, pl;
    ph.u.x = f2bf(acc.x); pl.u.x = f2bf(acc.x - bf2f(ph.u.x));
    ph.u.y = f2bf(acc.y); pl.u.y = f2bf(acc.y - bf2f(ph.u.y));
    ph.u.z = f2bf(acc.z); pl.u.z = f2bf(acc.z - bf2f(ph.u.z));
    ph.u.w = f2bf(acc.w); pl.u.w = f2bf(acc.w - bf2f(ph.u.w));
    size_t o = (size_t)n * KDIM + e * 256 + lane * 4;   // 8B-aligned
    __builtin_nontemporal_store(ph.ll, (unsigned long long*)(Xh + o));
    __builtin_nontemporal_store(pl.ll, (unsigned long long*)(Xl + o));
    if (lane == 0) ind[wid] = (cntv > 0) ? 1.f : 0.f;
}

// ---------------------------------------------------------------------------
// W conversion, both layers in one launch:
// W1[ET,256,256] -> W1h/W1l[256,768]; W2[ET,128,256] -> W2h/W2l[128,768]
// ---------------------------------------------------------------------------
#define W1ELEMS (ET * D_HID * 256)
#define W2ELEMS (ET * D_OUT * 256)
__global__ void wconv2_kernel(const float* __restrict__ W1, const float* __restrict__ W2,
                              unsigned short* __restrict__ W1h, unsigned short* __restrict__ W1l,
                              unsigned short* __restrict__ W2h, unsigned short* __restrict__ W2l) {
    int i = blockIdx.x * blockDim.x + threadIdx.x;
    if (i >= W1ELEMS + W2ELEMS) return;
    const float* W; unsigned short *Wh, *Wl; int Dout, k;
    if (i < W1ELEMS) { W = W1; Wh = W1h; Wl = W1l; Dout = D_HID; k = i; }
    else             { W = W2; Wh = W2h; Wl = W2l; Dout = D_OUT; k = i - W1ELEMS; }
    int f = k & 255;
    int t = k >> 8;            // e*Dout + co
    int e = t / Dout;
    int co = t - e * Dout;
    float w = W[k];
    unsigned short h = f2bf(w);
    float rem = w - bf2f(h);
    unsigned short l = f2bf(rem);
    int o = co * KDIM + e * 256 + f;
    Wh[o] = h; Wl[o] = l;
}

// ---------------------------------------------------------------------------
// Split-bf16 MFMA GEMM: out[M,Dout] = X[M,768] @ W[Dout,768]^T
//   acc += Ah*Bh + Ah*Bl + Al*Bh   (Al*Bl dropped, ~2^-18 relative)
// 128x128 tile, BK=32, 4 waves (2x2), each wave 64x64 = 4x4 fragments of
// 16x16x32. LDS fragment-linear (conflict-free by construction), DOUBLE-
// BUFFERED: stage K-step t+1 while computing t; one barrier per K-step.
// Epilogue: + sum_e ind[e][row]*bias[e][col], ACT=1 -> leaky_relu(0.01).
// ---------------------------------------------------------------------------
template<int ACT>
__global__ __launch_bounds__(256) void mfma_gemm(
    const unsigned short* __restrict__ Xh, const unsigned short* __restrict__ Xl,
    const unsigned short* __restrict__ Wh, const unsigned short* __restrict__ Wl,
    const float* __restrict__ bias, const float* __restrict__ ind,
    float* __restrict__ out, int M, int Dout) {
    // 2 x 32 KB halves: [Ah | Al | Bh | Bl] x 8 chunks x 512 ushorts
    __shared__ __align__(16) unsigned short smem[2 * 16384];
    const int tid  = threadIdx.x;
    const int lane = tid & 63;
    const int wid  = tid >> 6;           // 0..3
    const int wr   = wid >> 1, wc = wid & 1;
    const int rb   = blockIdx.x * 128;
    const int cb   = blockIdx.y * 128;
    const int lrow = lane & 15;
    const int lcol = (lane >> 4) * 8;    // bf16 element offset within 32-K

    f32x4 acc[4][4];
    #pragma unroll
    for (int i = 0; i < 4; ++i)
        #pragma unroll
        for (int j = 0; j < 4; ++j)
            acc[i][j] = (f32x4){0.f, 0.f, 0.f, 0.f};

    // staging pointers: wave stages subs {2*wid, 2*wid+1} of each array
    const unsigned short* ga_h[2];
    const unsigned short* ga_l[2];
    const unsigned short* gb_h[2];
    const unsigned short* gb_l[2];
    #pragma unroll
    for (int s = 0; s < 2; ++s) {
        int sub  = 2 * wid + s;
        size_t ao = (size_t)(rb + sub * 16 + lrow) * KDIM + lcol;  // rows < MPAD
        size_t bo = (size_t)(cb + sub * 16 + lrow) * KDIM + lcol;
        ga_h[s] = Xh + ao;  ga_l[s] = Xl + ao;
        gb_h[s] = Wh + bo;  gb_l[s] = Wl + bo;
    }

    // prologue: stage K-step 0 into half 0
    #pragma unroll
    for (int s = 0; s < 2; ++s) {
        int sub = 2 * wid + s;
        glds16(ga_h[s], &smem[0 * 4096 + sub * 512]);
        glds16(ga_l[s], &smem[1 * 4096 + sub * 512]);
        glds16(gb_h[s], &smem[2 * 4096 + sub * 512]);
        glds16(gb_l[s], &smem[3 * 4096 + sub * 512]);
    }
    __syncthreads();

    int cur = 0;
    for (int t = 0; t < KDIM / 32; ++t) {
        // stage next K-step into the other half (hidden under MFMA below)
        if (t < KDIM / 32 - 1) {
            unsigned short* sb = &smem[(cur ^ 1) * 16384];
            int nk = (t + 1) * 32;
            #pragma unroll
            for (int s = 0; s < 2; ++s) {
                int sub = 2 * wid + s;
                glds16(ga_h[s] + nk, &sb[0 * 4096 + sub * 512]);
                glds16(ga_l[s] + nk, &sb[1 * 4096 + sub * 512]);
                glds16(gb_h[s] + nk, &sb[2 * 4096 + sub * 512]);
                glds16(gb_l[s] + nk, &sb[3 * 4096 + sub * 512]);
            }
        }
        const unsigned short* sc = &smem[cur * 16384];
        bhalf8 ah[4], al[4], bh[4], bl[4];
        #pragma unroll
        for (int q = 0; q < 4; ++q) {
            ah[q] = *(const bhalf8*)&sc[0 * 4096 + (wr * 4 + q) * 512 + lane * 8];
            al[q] = *(const bhalf8*)&sc[1 * 4096 + (wr * 4 + q) * 512 + lane * 8];
            bh[q] = *(const bhalf8*)&sc[2 * 4096 + (wc * 4 + q) * 512 + lane * 8];
            bl[q] = *(const bhalf8*)&sc[3 * 4096 + (wc * 4 + q) * 512 + lane * 8];
        }
        #pragma unroll
        for (int i = 0; i < 4; ++i)
            #pragma unroll
            for (int j = 0; j < 4; ++j) {
                acc[i][j] = __builtin_amdgcn_mfma_f32_16x16x32_bf16(ah[i], bh[j], acc[i][j], 0, 0, 0);
                acc[i][j] = __builtin_amdgcn_mfma_f32_16x16x32_bf16(ah[i], bl[j], acc[i][j], 0, 0, 0);
                acc[i][j] = __builtin_amdgcn_mfma_f32_16x16x32_bf16(al[i], bh[j], acc[i][j], 0, 0, 0);
            }
        __syncthreads();
        cur ^= 1;
    }

    // epilogue: C/D layout col=lane&15, row=(lane>>4)*4+reg
    const int orow = (lane >> 4) * 4;
    const int ocol = lane & 15;
    #pragma unroll
    for (int i = 0; i < 4; ++i) {
        int rbase = rb + wr * 64 + i * 16 + orow;
        #pragma unroll
        for (int q = 0; q < 4; ++q) {
            int r = rbase + q;
            if (r >= M) continue;
            float i0 = ind[0 * N_NODES + r];
            float i1 = ind[1 * N_NODES + r];
            float i2 = ind[2 * N_NODES + r];
            #pragma unroll
            for (int j = 0; j < 4; ++j) {
                int col = cb + wc * 64 + j * 16 + ocol;
                float t = acc[i][j][q] + i0 * bias[0 * Dout + col]
                                       + i1 * bias[1 * Dout + col]
                                       + i2 * bias[2 * Dout + col];
                if (ACT) t = (t > 0.f) ? t : 0.01f * t;
                out[(size_t)r * Dout + col] = t;
            }
        }
    }
}

// ---------------------------------------------------------------------------
// Launch
// ---------------------------------------------------------------------------
extern "C" void kernel_launch(void* const* d_in, const int* in_sizes, int n_in,
                              void* d_out, int out_size, void* d_ws, size_t ws_size,
                              hipStream_t stream) {
    const float* x      = (const float*)d_in[0];
    const int*   edges1 = (const int*)d_in[1];
    const int*   edges2 = (const int*)d_in[2];
    const float* W1     = (const float*)d_in[3];
    const float* b1     = (const float*)d_in[4];
    const float* W2     = (const float*)d_in[5];
    const float* b2     = (const float*)d_in[6];
    float* out = (float*)d_out;

    // workspace carve-up (~220 MB)
    char* ws = (char*)d_ws;
    size_t p = 0;
    auto alloc = [&](size_t bytes) { size_t o = p; p = (p + bytes + 255) & ~(size_t)255; return o; };
    unsigned short* Xh  = (unsigned short*)(ws + alloc((size_t)MPAD * KDIM * 2));  // 76.9 MB
    unsigned short* Xl  = (unsigned short*)(ws + alloc((size_t)MPAD * KDIM * 2));  // 76.9 MB
    float* h            = (float*)(ws + alloc((size_t)N_NODES * D_HID * 4));       // 51.2 MB
    unsigned short* W1h = (unsigned short*)(ws + alloc((size_t)D_HID * KDIM * 2));
    unsigned short* W1l = (unsigned short*)(ws + alloc((size_t)D_HID * KDIM * 2));
    unsigned short* W2h = (unsigned short*)(ws + alloc((size_t)D_OUT * KDIM * 2));
    unsigned short* W2l = (unsigned short*)(ws + alloc((size_t)D_OUT * KDIM * 2));
    int*   cnt    = (int*)(ws + alloc((size_t)NTOT2 * 4));
    int*   rp     = (int*)(ws + alloc((size_t)(NTOT2 + 1) * 4));
    int*   cursor = (int*)(ws + alloc((size_t)NTOT2 * 4));
    int*   esrc   = (int*)(ws + alloc((size_t)ETOT2 * 4));
    float* ind    = (float*)(ws + alloc((size_t)NTOT * 4));
    int*   bsum   = (int*)(ws + alloc(512 * 4));
    int*   bbase  = (int*)(ws + alloc(512 * 4));
    (void)ws_size; (void)in_sizes; (void)n_in; (void)out_size;

    const int EB2 = (ETOT2 + 255) / 256;    // 7032
    const int AB  = (NTOT * 64 + 255) / 256;
    const int MB  = MPAD / 128;             // 391
    const int S3  = (NTOT2 + 255) / 256;

    // ---- shared preprocessing: weights + both CSRs in one pass ----
    wconv2_kernel<<<(W1ELEMS + W2ELEMS + 255) / 256, 256, 0, stream>>>(W1, W2, W1h, W1l, W2h, W2l);
    hipMemsetAsync(cnt, 0, (size_t)NTOT2 * 4, stream);
    hist2_kernel<<<EB2, 256, 0, stream>>>(edges1, edges2, cnt);
    scan1_kernel<<<NB2, 256, 0, stream>>>(cnt, rp, bsum);
    scan2_kernel<<<1, 512, 0, stream>>>(bsum, bbase);
    scan3_kernel<<<S3, 256, 0, stream>>>(rp, cursor, bbase);
    fill2_kernel<<<EB2, 256, 0, stream>>>(edges1, edges2, cursor, esrc);

    // ---- layer 1 ----
    agg_kernel<<<AB, 256, 0, stream>>>(x, rp, esrc, 0, Xh, Xl, ind);
    mfma_gemm<1><<<dim3(MB, D_HID / 128), 256, 0, stream>>>(Xh, Xl, W1h, W1l, b1, ind, h,
                                                            N_NODES, D_HID);
    // ---- layer 2 ----
    agg_kernel<<<AB, 256, 0, stream>>>(h, rp, esrc, NTOT, Xh, Xl, ind);
    mfma_gemm<0><<<dim3(MB, D_OUT / 128), 256, 0, stream>>>(Xh, Xl, W2h, W2l, b2, ind, out,
                                                            N_NODES, D_OUT);
}

// Round 11
// 573.816 us; speedup vs baseline: 1.3138x; 1.3138x over previous
//
#include <hip/hip_runtime.h>
#include <hip/hip_bf16.h>
#include <stdint.h>

// Problem constants (match reference)
#define N_NODES 50000
#define N_EDGES 300000
#define ET      3
#define D_IN    256
#define D_HID   256
#define D_OUT   128
#define KDIM    768          // ET * 256, fused-K for the single GEMM per layer
#define MPAD    50048        // 391 * 128 (GEMM row-tile padded)
#define NTOT    (ET * N_NODES)          // 150000 merged (etype,node) slots per layer
#define ETOT    (ET * N_EDGES)          // 900000 edges per layer
#define NTOT2   (2 * NTOT)              // both layers
#define ETOT2   (2 * ETOT)
#define NB2     ((NTOT2 + 1023) / 1024) // 293 scan blocks

typedef short bhalf8 __attribute__((ext_vector_type(8)));   // 8 bf16 (4 VGPRs)
typedef float f32x4  __attribute__((ext_vector_type(4)));

// bf16 helpers (RNE), bit-level to avoid header API differences
__device__ __forceinline__ unsigned short f2bf(float f) {
    union { float f; uint32_t u; } c; c.f = f;
    uint32_t u = c.u;
    uint32_t r = (u + 0x7fff + ((u >> 16) & 1)) >> 16;
    return (unsigned short)r;
}
__device__ __forceinline__ float bf2f(unsigned short b) {
    union { uint32_t u; float f; } c; c.u = ((uint32_t)b) << 16;
    return c.f;
}

__device__ __forceinline__ void glds16(const void* g, const void* l) {
    __builtin_amdgcn_global_load_lds(
        (const __attribute__((address_space(1))) unsigned int*)g,
        (__attribute__((address_space(3))) unsigned int*)l, 16, 0, 0);
}

// ---------------------------------------------------------------------------
// CSR build, BOTH graphs at once (merged slot space [2*NTOT]):
//   slot = layer*NTOT + e*N_NODES + dst
// ---------------------------------------------------------------------------

__global__ void hist2_kernel(const int* __restrict__ edges1, const int* __restrict__ edges2,
                             int* __restrict__ cnt) {
    int i = blockIdx.x * blockDim.x + threadIdx.x;
    if (i >= ETOT2) return;
    int layer = i / ETOT;
    int k = i - layer * ETOT;
    int e = k / N_EDGES;
    int j = k - e * N_EDGES;
    const int* edges = layer ? edges2 : edges1;
    int dst = edges[(e * 2 + 1) * N_EDGES + j];
    atomicAdd(&cnt[layer * NTOT + e * N_NODES + dst], 1);
}

// scan1: block b scans its 1024 counts (4/thread), writes block-local
// exclusive positions into rp and the block total into bsum[b].
__global__ __launch_bounds__(256) void scan1_kernel(const int* __restrict__ cnt,
                                                    int* __restrict__ rp,
                                                    int* __restrict__ bsum) {
    int b = blockIdx.x, t = threadIdx.x;
    int idx = b * 1024 + t * 4;
    int4 v = make_int4(0, 0, 0, 0);
    if (idx + 3 < NTOT2) v = *(const int4*)&cnt[idx];
    else {
        if (idx + 0 < NTOT2) v.x = cnt[idx + 0];
        if (idx + 1 < NTOT2) v.y = cnt[idx + 1];
        if (idx + 2 < NTOT2) v.z = cnt[idx + 2];
        if (idx + 3 < NTOT2) v.w = cnt[idx + 3];
    }
    int s = v.x + v.y + v.z + v.w;
    int lane = t & 63, w = t >> 6;
    int inc = s;
    #pragma unroll
    for (int d = 1; d < 64; d <<= 1) {
        int u = __shfl_up(inc, d, 64);
        if (lane >= d) inc += u;
    }
    __shared__ int ws[4];
    if (lane == 63) ws[w] = inc;
    __syncthreads();
    int wbase = 0;
    for (int i2 = 0; i2 < w; ++i2) wbase += ws[i2];
    int ebase = wbase + inc - s;   // block-local exclusive base for this thread
    if (idx + 0 < NTOT2) rp[idx + 0] = ebase;
    if (idx + 1 < NTOT2) rp[idx + 1] = ebase + v.x;
    if (idx + 2 < NTOT2) rp[idx + 2] = ebase + v.x + v.y;
    if (idx + 3 < NTOT2) rp[idx + 3] = ebase + v.x + v.y + v.z;
    if (t == 0) bsum[b] = ws[0] + ws[1] + ws[2] + ws[3];
}

// scan2: one block (512 threads); exclusive scan of the 293 block sums.
__global__ __launch_bounds__(512) void scan2_kernel(const int* __restrict__ bsum,
                                                    int* __restrict__ bbase) {
    int t = threadIdx.x;
    __shared__ int sh[512];
    int v = (t < NB2) ? bsum[t] : 0;
    sh[t] = v;
    __syncthreads();
    #pragma unroll
    for (int d = 1; d < 512; d <<= 1) {
        int u = (t >= d) ? sh[t - d] : 0;
        __syncthreads();
        sh[t] += u;
        __syncthreads();
    }
    if (t < NB2) bbase[t] = sh[t] - v;   // exclusive
}

// scan3: add block bases; emit final rowptr + cursor copy + sentinel.
__global__ void scan3_kernel(int* __restrict__ rp, int* __restrict__ cursor,
                             const int* __restrict__ bbase) {
    int i = blockIdx.x * blockDim.x + threadIdx.x;
    if (i < NTOT2) {
        int v = rp[i] + bbase[i >> 10];
        rp[i] = v;
        cursor[i] = v;
    }
    if (i == 0) rp[NTOT2] = ETOT2;
}

__global__ void fill2_kernel(const int* __restrict__ edges1, const int* __restrict__ edges2,
                             int* __restrict__ cursor, int* __restrict__ esrc) {
    int i = blockIdx.x * blockDim.x + threadIdx.x;
    if (i >= ETOT2) return;
    int layer = i / ETOT;
    int k = i - layer * ETOT;
    int e = k / N_EDGES;
    int j = k - e * N_EDGES;
    const int* edges = layer ? edges2 : edges1;
    int src = edges[(e * 2 + 0) * N_EDGES + j];
    int dst = edges[(e * 2 + 1) * N_EDGES + j];
    int p = atomicAdd(&cursor[layer * NTOT + e * N_NODES + dst], 1);   // global position
    esrc[p] = src;
}

// ---------------------------------------------------------------------------
// x -> bf16 conversion. 4 elems/thread.
// ---------------------------------------------------------------------------
__global__ void xconv_kernel(const float* __restrict__ x, unsigned short* __restrict__ xb) {
    int i = blockIdx.x * blockDim.x + threadIdx.x;
    if (i * 4 >= N_NODES * 256) return;
    float4 v = *(const float4*)(x + (size_t)i * 4);
    ushort4 o;
    o.x = f2bf(v.x); o.y = f2bf(v.y); o.z = f2bf(v.z); o.w = f2bf(v.w);
    *(ushort4*)(xb + (size_t)i * 4) = o;
}

// ---------------------------------------------------------------------------
// Aggregation (pull), bf16 source: one wave per (etype, node). Lane t owns
// channels [4t,4t+4): ushort4 (8B) per gathered row -> 512B/row coalesced.
// fp32 accumulate, mean, single bf16 output Xh[n][e*256+c]. ind = (cnt>0).
// ---------------------------------------------------------------------------
__global__ void agg_kernel(const unsigned short* __restrict__ in, const int* __restrict__ rp,
                           const int* __restrict__ esrc, int base,
                           unsigned short* __restrict__ Xh, float* __restrict__ ind) {
    int wid = (blockIdx.x * blockDim.x + threadIdx.x) >> 6;
    int lane = threadIdx.x & 63;
    if (wid >= NTOT) return;
    int e = wid / N_NODES;
    int n = wid - e * N_NODES;
    int r0 = rp[base + wid];
    int r1 = rp[base + wid + 1];
    int cntv = r1 - r0;
    float4 acc = make_float4(0.f, 0.f, 0.f, 0.f);
    int j = r0;
    for (; j + 4 <= r1; j += 4) {
        int s0 = esrc[j + 0];
        int s1 = esrc[j + 1];
        int s2 = esrc[j + 2];
        int s3 = esrc[j + 3];
        ushort4 v0 = *((const ushort4*)(in + (size_t)s0 * 256) + lane);
        ushort4 v1 = *((const ushort4*)(in + (size_t)s1 * 256) + lane);
        ushort4 v2 = *((const ushort4*)(in + (size_t)s2 * 256) + lane);
        ushort4 v3 = *((const ushort4*)(in + (size_t)s3 * 256) + lane);
        acc.x += bf2f(v0.x) + bf2f(v1.x) + bf2f(v2.x) + bf2f(v3.x);
        acc.y += bf2f(v0.y) + bf2f(v1.y) + bf2f(v2.y) + bf2f(v3.y);
        acc.z += bf2f(v0.z) + bf2f(v1.z) + bf2f(v2.z) + bf2f(v3.z);
        acc.w += bf2f(v0.w) + bf2f(v1.w) + bf2f(v2.w) + bf2f(v3.w);
    }
    for (; j < r1; ++j) {
        int s = esrc[j];
        ushort4 v = *((const ushort4*)(in + (size_t)s * 256) + lane);
        acc.x += bf2f(v.x); acc.y += bf2f(v.y); acc.z += bf2f(v.z); acc.w += bf2f(v.w);
    }
    float sc = (cntv > 0) ? (1.f / (float)cntv) : 0.f;
    ushort4 hv;
    hv.x = f2bf(acc.x * sc); hv.y = f2bf(acc.y * sc);
    hv.z = f2bf(acc.z * sc); hv.w = f2bf(acc.w * sc);
    *((ushort4*)(Xh + (size_t)n * KDIM + e * 256) + lane) = hv;
    if (lane == 0) ind[wid] = (cntv > 0) ? 1.f : 0.f;
}

// ---------------------------------------------------------------------------
// W conversion, both layers in one launch (split hi/lo kept on B side):
// W1[ET,256,256] -> W1h/W1l[256,768]; W2[ET,128,256] -> W2h/W2l[128,768]
// ---------------------------------------------------------------------------
#define W1ELEMS (ET * D_HID * 256)
#define W2ELEMS (ET * D_OUT * 256)
__global__ void wconv2_kernel(const float* __restrict__ W1, const float* __restrict__ W2,
                              unsigned short* __restrict__ W1h, unsigned short* __restrict__ W1l,
                              unsigned short* __restrict__ W2h, unsigned short* __restrict__ W2l) {
    int i = blockIdx.x * blockDim.x + threadIdx.x;
    if (i >= W1ELEMS + W2ELEMS) return;
    const float* W; unsigned short *Wh, *Wl; int Dout, k;
    if (i < W1ELEMS) { W = W1; Wh = W1h; Wl = W1l; Dout = D_HID; k = i; }
    else             { W = W2; Wh = W2h; Wl = W2l; Dout = D_OUT; k = i - W1ELEMS; }
    int f = k & 255;
    int t = k >> 8;            // e*Dout + co
    int e = t / Dout;
    int co = t - e * Dout;
    float w = W[k];
    unsigned short h = f2bf(w);
    float rem = w - bf2f(h);
    unsigned short l = f2bf(rem);
    int o = co * KDIM + e * 256 + f;
    Wh[o] = h; Wl[o] = l;
}

// ---------------------------------------------------------------------------
// MFMA GEMM, A-single x B-split: out = X @ (Wh+Wl)^T
// 128x128 tile, BK=32, 4 waves (2x2), 32 MFMA/K-step, LDS fragment-linear,
// double-buffered 2x24KB. Epilogue: + sum_e ind*bias, ACT -> leaky_relu,
// OBF -> write bf16 (layer-1 h feeds the next gather), else fp32.
// ---------------------------------------------------------------------------
template<int ACT, int OBF>
__global__ __launch_bounds__(256) void mfma_gemm(
    const unsigned short* __restrict__ Xh,
    const unsigned short* __restrict__ Wh, const unsigned short* __restrict__ Wl,
    const float* __restrict__ bias, const float* __restrict__ ind,
    void* __restrict__ outp, int M, int Dout) {
    // 2 halves x [A | Bh | Bl] x 8 chunks x 512 ushorts = 2 x 24 KB
    __shared__ __align__(16) unsigned short smem[2 * 12288];
    const int tid  = threadIdx.x;
    const int lane = tid & 63;
    const int wid  = tid >> 6;           // 0..3
    const int wr   = wid >> 1, wc = wid & 1;
    const int rb   = blockIdx.x * 128;
    const int cb   = blockIdx.y * 128;
    const int lrow = lane & 15;
    const int lcol = (lane >> 4) * 8;    // bf16 element offset within 32-K

    f32x4 acc[4][4];
    #pragma unroll
    for (int i = 0; i < 4; ++i)
        #pragma unroll
        for (int j = 0; j < 4; ++j)
            acc[i][j] = (f32x4){0.f, 0.f, 0.f, 0.f};

    const unsigned short* ga[2];
    const unsigned short* gbh[2];
    const unsigned short* gbl[2];
    #pragma unroll
    for (int s = 0; s < 2; ++s) {
        int sub  = 2 * wid + s;
        size_t ao = (size_t)(rb + sub * 16 + lrow) * KDIM + lcol;  // rows < MPAD
        size_t bo = (size_t)(cb + sub * 16 + lrow) * KDIM + lcol;
        ga[s]  = Xh + ao;
        gbh[s] = Wh + bo;
        gbl[s] = Wl + bo;
    }

    // prologue: stage K-step 0 into half 0
    #pragma unroll
    for (int s = 0; s < 2; ++s) {
        int sub = 2 * wid + s;
        glds16(ga[s],  &smem[0 * 4096 + sub * 512]);
        glds16(gbh[s], &smem[1 * 4096 + sub * 512]);
        glds16(gbl[s], &smem[2 * 4096 + sub * 512]);
    }
    __syncthreads();

    int cur = 0;
    for (int t = 0; t < KDIM / 32; ++t) {
        if (t < KDIM / 32 - 1) {
            unsigned short* sb = &smem[(cur ^ 1) * 12288];
            int nk = (t + 1) * 32;
            #pragma unroll
            for (int s = 0; s < 2; ++s) {
                int sub = 2 * wid + s;
                glds16(ga[s] + nk,  &sb[0 * 4096 + sub * 512]);
                glds16(gbh[s] + nk, &sb[1 * 4096 + sub * 512]);
                glds16(gbl[s] + nk, &sb[2 * 4096 + sub * 512]);
            }
        }
        const unsigned short* sc = &smem[cur * 12288];
        bhalf8 ah[4], bh[4], bl[4];
        #pragma unroll
        for (int q = 0; q < 4; ++q) {
            ah[q] = *(const bhalf8*)&sc[0 * 4096 + (wr * 4 + q) * 512 + lane * 8];
            bh[q] = *(const bhalf8*)&sc[1 * 4096 + (wc * 4 + q) * 512 + lane * 8];
            bl[q] = *(const bhalf8*)&sc[2 * 4096 + (wc * 4 + q) * 512 + lane * 8];
        }
        #pragma unroll
        for (int i = 0; i < 4; ++i)
            #pragma unroll
            for (int j = 0; j < 4; ++j) {
                acc[i][j] = __builtin_amdgcn_mfma_f32_16x16x32_bf16(ah[i], bh[j], acc[i][j], 0, 0, 0);
                acc[i][j] = __builtin_amdgcn_mfma_f32_16x16x32_bf16(ah[i], bl[j], acc[i][j], 0, 0, 0);
            }
        __syncthreads();
        cur ^= 1;
    }

    // epilogue: C/D layout col=lane&15, row=(lane>>4)*4+reg
    const int orow = (lane >> 4) * 4;
    const int ocol = lane & 15;
    #pragma unroll
    for (int i = 0; i < 4; ++i) {
        int rbase = rb + wr * 64 + i * 16 + orow;
        #pragma unroll
        for (int q = 0; q < 4; ++q) {
            int r = rbase + q;
            if (r >= M) continue;
            float i0 = ind[0 * N_NODES + r];
            float i1 = ind[1 * N_NODES + r];
            float i2 = ind[2 * N_NODES + r];
            #pragma unroll
            for (int j = 0; j < 4; ++j) {
                int col = cb + wc * 64 + j * 16 + ocol;
                float t = acc[i][j][q] + i0 * bias[0 * Dout + col]
                                       + i1 * bias[1 * Dout + col]
                                       + i2 * bias[2 * Dout + col];
                if (ACT) t = (t > 0.f) ? t : 0.01f * t;
                if (OBF) ((unsigned short*)outp)[(size_t)r * Dout + col] = f2bf(t);
                else     ((float*)outp)[(size_t)r * Dout + col] = t;
            }
        }
    }
}

// ---------------------------------------------------------------------------
// Launch
// ---------------------------------------------------------------------------
extern "C" void kernel_launch(void* const* d_in, const int* in_sizes, int n_in,
                              void* d_out, int out_size, void* d_ws, size_t ws_size,
                              hipStream_t stream) {
    const float* x      = (const float*)d_in[0];
    const int*   edges1 = (const int*)d_in[1];
    const int*   edges2 = (const int*)d_in[2];
    const float* W1     = (const float*)d_in[3];
    const float* b1     = (const float*)d_in[4];
    const float* W2     = (const float*)d_in[5];
    const float* b2     = (const float*)d_in[6];
    float* out = (float*)d_out;

    // workspace carve-up (~145 MB)
    char* ws = (char*)d_ws;
    size_t p = 0;
    auto alloc = [&](size_t bytes) { size_t o = p; p = (p + bytes + 255) & ~(size_t)255; return o; };
    unsigned short* Xh  = (unsigned short*)(ws + alloc((size_t)MPAD * KDIM * 2));    // 76.9 MB
    unsigned short* xb  = (unsigned short*)(ws + alloc((size_t)N_NODES * 256 * 2));  // 25.6 MB
    unsigned short* hb  = (unsigned short*)(ws + alloc((size_t)N_NODES * 256 * 2));  // 25.6 MB
    unsigned short* W1h = (unsigned short*)(ws + alloc((size_t)D_HID * KDIM * 2));
    unsigned short* W1l = (unsigned short*)(ws + alloc((size_t)D_HID * KDIM * 2));
    unsigned short* W2h = (unsigned short*)(ws + alloc((size_t)D_OUT * KDIM * 2));
    unsigned short* W2l = (unsigned short*)(ws + alloc((size_t)D_OUT * KDIM * 2));
    int*   cnt    = (int*)(ws + alloc((size_t)NTOT2 * 4));
    int*   rp     = (int*)(ws + alloc((size_t)(NTOT2 + 1) * 4));
    int*   cursor = (int*)(ws + alloc((size_t)NTOT2 * 4));
    int*   esrc   = (int*)(ws + alloc((size_t)ETOT2 * 4));
    float* ind    = (float*)(ws + alloc((size_t)NTOT * 4));
    int*   bsum   = (int*)(ws + alloc(512 * 4));
    int*   bbase  = (int*)(ws + alloc(512 * 4));
    (void)ws_size; (void)in_sizes; (void)n_in; (void)out_size;

    const int EB2 = (ETOT2 + 255) / 256;    // 7032
    const int AB  = (NTOT * 64 + 255) / 256;
    const int MB  = MPAD / 128;             // 391
    const int S3  = (NTOT2 + 255) / 256;

    // ---- shared preprocessing: weights + x-bf16 + both CSRs ----
    wconv2_kernel<<<(W1ELEMS + W2ELEMS + 255) / 256, 256, 0, stream>>>(W1, W2, W1h, W1l, W2h, W2l);
    xconv_kernel<<<(N_NODES * 256 / 4 + 255) / 256, 256, 0, stream>>>(x, xb);
    hipMemsetAsync(cnt, 0, (size_t)NTOT2 * 4, stream);
    hist2_kernel<<<EB2, 256, 0, stream>>>(edges1, edges2, cnt);
    scan1_kernel<<<NB2, 256, 0, stream>>>(cnt, rp, bsum);
    scan2_kernel<<<1, 512, 0, stream>>>(bsum, bbase);
    scan3_kernel<<<S3, 256, 0, stream>>>(rp, cursor, bbase);
    fill2_kernel<<<EB2, 256, 0, stream>>>(edges1, edges2, cursor, esrc);

    // ---- layer 1 ----
    agg_kernel<<<AB, 256, 0, stream>>>(xb, rp, esrc, 0, Xh, ind);
    mfma_gemm<1, 1><<<dim3(MB, D_HID / 128), 256, 0, stream>>>(Xh, W1h, W1l, b1, ind, hb,
                                                               N_NODES, D_HID);
    // ---- layer 2 ----
    agg_kernel<<<AB, 256, 0, stream>>>(hb, rp, esrc, NTOT, Xh, ind);
    mfma_gemm<0, 0><<<dim3(MB, D_OUT / 128), 256, 0, stream>>>(Xh, W2h, W2l, b2, ind, out,
                                                               N_NODES, D_OUT);
}